// Round 2
// baseline (287.248 us; speedup 1.0000x reference)
//
#include <hip/hip_runtime.h>
#include <math.h>

// Problem constants (fixed by reference: B=8, C=3, H=W=1024)
constexpr int BC = 24;     // B*C point-set pairs
constexpr int N  = 1024;   // points per set
constexpr int D  = 1024;   // point dimension
constexpr int TILE = 128;  // 128x128 output tile per block
constexpr int SKF = 40;    // fallback kernel LDS stride (bf16)

typedef short short8 __attribute__((ext_vector_type(8)));
typedef float f32x4  __attribute__((ext_vector_type(4)));
typedef long lng2    __attribute__((ext_vector_type(2)));   // two i64 fp8 fragments

#define FINF 3.402823466e+38f

// ---- Swizzled fp8 layout (used identically by prep-write and tile-read) ----
// Super-tile ST = (bc, R = row>>4, Kp = k>>6): 16 rows x 64 k = 1024 fp8 = 1 KB.
// Within: r16 = row&15, dose = (k>>5)&1, quad = (k>>3)&3, j = k&7.
// lane = r16 | (quad<<4); flat byte = ST*1024 + lane*16 + dose*8 + j.
// Tile kernel reads a wave fragment pair (doses 0,1 of one 16-row tile) as one
// coalesced 1-KB global_load_dwordx4 (16 B/lane). Prep READS contiguously and
// scatters dword STORES into this layout (permutation rides the store side;
// stores are fire-and-forget, and all sectors are fully covered per 16-row
// block so L2 write-combines them).

// Pack two fp32 -> two bf16 (fallback path only). HW-verified R2-R5.
__device__ inline unsigned pk_bf16(float a, float b) {
    unsigned ua = __float_as_uint(a) + 0x8000u;
    unsigned ub = __float_as_uint(b) + 0x8000u;
    return __builtin_amdgcn_perm(ub, ua, 0x07060302);
}

// 4 floats -> one 32-bit word of 4 fp8-e4m3 (OCP on gfx950), RTNE.
__device__ inline int pk_fp8x4(float a, float b, float c, float d) {
    int w = __builtin_amdgcn_cvt_pk_fp8_f32(a, b, 0, false);   // bytes 0,1
    w = __builtin_amdgcn_cvt_pk_fp8_f32(c, d, w, true);        // bytes 2,3
    return w;
}

// ============================ FAST PATH ============================
// ---- Kernel 1g: contiguous-read prep (fp32 -> swizzled fp8) + exact norms ----
// 49152 rows total (2 tensors x 24576). 1536 blocks x 4 waves x 8 rows/wave.
// Per (row, q): lane holds k = q*256 + lane*4 .. +3. Swizzle decomposition:
//   Kp   = q*4 + (lane>>4)
//   dose = (lane>>3)&1, quad_o = (lane>>1)&3, j0 = (lane&1)*4
// -> store byte = ((row&~15) + q*4 + (lane>>4))*1024 + (row&15)*16
//                 + quad_o*256 + dose*8 + j0                (one dword per q)
// Reads: perfectly contiguous 1 KB per wave instruction. Norm: full row per
// wave -> in-register shfl reduction, single plain store (no atomics).
__global__ __launch_bounds__(256) void prep_kernel(const float* __restrict__ X,
                                                   const float* __restrict__ Y,
                                                   unsigned char* __restrict__ Xf8,
                                                   unsigned char* __restrict__ Yf8,
                                                   float* __restrict__ xn,
                                                   float* __restrict__ yn) {
    int wave = threadIdx.x >> 6, lane = threadIdx.x & 63;
    int rid0 = (blockIdx.x * 4 + wave) * 8;        // 0 .. 49144, step 8
    bool isY = rid0 >= 24576;                      // 8 | 24576 -> no straddle
    int row0 = isY ? rid0 - 24576 : rid0;          // within-tensor row index
    const float* __restrict__ src = (isY ? Y : X) + (size_t)row0 * D + lane * 4;
    unsigned char* __restrict__ dst = isY ? Yf8 : Xf8;
    float* __restrict__ nrm = isY ? yn : xn;

    int KpL   = lane >> 4;
    int inner = (((lane >> 1) & 3) << 8) | (((lane >> 3) & 1) << 3) | ((lane & 1) << 2);
    // store addr for (r, q) = dbase + q*4096 + r*16
    unsigned char* dbase = dst + (size_t)((row0 & ~15) + KpL) * 1024
                               + (row0 & 15) * 16 + inner;

    // 3-slot register ring, 2-row lookahead (8-12 loads in flight per wave).
    float4 A[4], Bv[4], Cv[4];
    #pragma unroll
    for (int q = 0; q < 4; q++) A[q]  = *(const float4*)(src + q * 256);
    #pragma unroll
    for (int q = 0; q < 4; q++) Bv[q] = *(const float4*)(src + D + q * 256);

    #pragma unroll
    for (int r = 0; r < 8; r++) {
        if (r < 6) {
            #pragma unroll
            for (int q = 0; q < 4; q++)
                Cv[q] = *(const float4*)(src + (size_t)(r + 2) * D + q * 256);
        }
        float s = 0.f;
        #pragma unroll
        for (int q = 0; q < 4; q++) {
            unsigned w = (unsigned)pk_fp8x4(A[q].x, A[q].y, A[q].z, A[q].w);
            *(unsigned*)(dbase + q * 4096 + r * 16) = w;
            s += A[q].x * A[q].x + A[q].y * A[q].y
               + A[q].z * A[q].z + A[q].w * A[q].w;
        }
        #pragma unroll
        for (int m = 1; m < 64; m <<= 1) s += __shfl_xor(s, m, 64);
        if (lane == 0) nrm[row0 + r] = s;          // exact fp32 row norm
        #pragma unroll
        for (int q = 0; q < 4; q++) { A[q] = Bv[q]; Bv[q] = Cv[q]; }
    }
}

// ---- Kernel 2f: zero-LDS fp8 MFMA tile kernel; frags straight from swizzled L2/L3 ----
__global__ __launch_bounds__(256, 3) void tile_f8_kernel(const unsigned char* __restrict__ Xf8,
                                                         const unsigned char* __restrict__ Yf8,
                                                         const float* __restrict__ xn,
                                                         const float* __restrict__ yn,
                                                         unsigned* __restrict__ rowmin,
                                                         unsigned* __restrict__ colmin) {
    int id = blockIdx.x;              // 0..1535; same-bc blocks are dispatch-adjacent
    int bc = id >> 6;
    int tn = (id >> 3) & 7, tm = id & 7;

    int wave = threadIdx.x >> 6, lane = threadIdx.x & 63;
    int wr = wave >> 1, wc = wave & 1;      // wave tile: rows wr*64, cols wc*64
    int quad = lane >> 4, tx = lane & 15;

    const unsigned char* Xb = Xf8 + (size_t)bc * 1024 * 1024;   // 1024 STs x 1 KB per bc
    const unsigned char* Yb = Yf8 + (size_t)bc * 1024 * 1024;
    // A STs: R = tn*8 + wr*4 + mi (mi stride = 16 STs = 16 KB); Kp stride = 1 KB.
    const unsigned char* ax = Xb + (size_t)(tn * 8 + wr * 4) * 16 * 1024 + lane * 16;
    const unsigned char* by = Yb + (size_t)(tm * 8 + wc * 4) * 16 * 1024 + lane * 16;

    f32x4 acc[4][4];
    #pragma unroll
    for (int i = 0; i < 4; i++)
        #pragma unroll
        for (int j = 0; j < 4; j++) acc[i][j] = (f32x4)0.f;

    // 2-deep register pipeline over 16 Kp super-doses (2 MFMA doses each).
    lng2 a[2][4], b[2][4];
    #pragma unroll
    for (int mi = 0; mi < 4; mi++) {
        a[0][mi] = *(const lng2*)(ax + mi * 16384);
        b[0][mi] = *(const lng2*)(by + mi * 16384);
    }
    #pragma unroll
    for (int Kp = 0; Kp < 16; Kp++) {
        int cur = Kp & 1, nxt = cur ^ 1;
        if (Kp < 15) {
            #pragma unroll
            for (int mi = 0; mi < 4; mi++) {
                a[nxt][mi] = *(const lng2*)(ax + mi * 16384 + (Kp + 1) * 1024);
                b[nxt][mi] = *(const lng2*)(by + mi * 16384 + (Kp + 1) * 1024);
            }
        }
        #pragma unroll
        for (int mi = 0; mi < 4; mi++)
            #pragma unroll
            for (int mj = 0; mj < 4; mj++)
                acc[mi][mj] = __builtin_amdgcn_mfma_f32_16x16x32_fp8_fp8(a[cur][mi].x, b[cur][mj].x, acc[mi][mj], 0, 0, 0);
        #pragma unroll
        for (int mi = 0; mi < 4; mi++)
            #pragma unroll
            for (int mj = 0; mj < 4; mj++)
                acc[mi][mj] = __builtin_amdgcn_mfma_f32_16x16x32_fp8_fp8(a[cur][mi].y, b[cur][mj].y, acc[mi][mj], 0, 0, 0);
    }

    // Epilogue. D-layout (shape-determined, dtype-independent): row = quad*4 + r, col = tx.
    int rbase = bc * N + tn * TILE + wr * 64;
    int cbase = bc * N + tm * TILE + wc * 64;
    float xnr[4][4], ynr[4];
    #pragma unroll
    for (int mi = 0; mi < 4; mi++)
        #pragma unroll
        for (int r = 0; r < 4; r++) xnr[mi][r] = xn[rbase + mi * 16 + quad * 4 + r];
    #pragma unroll
    for (int mj = 0; mj < 4; mj++) ynr[mj] = yn[cbase + mj * 16 + tx];

    float rmin[4][4], cmin[4];
    #pragma unroll
    for (int mi = 0; mi < 4; mi++)
        #pragma unroll
        for (int r = 0; r < 4; r++) rmin[mi][r] = FINF;
    #pragma unroll
    for (int mj = 0; mj < 4; mj++) cmin[mj] = FINF;

    #pragma unroll
    for (int mi = 0; mi < 4; mi++)
        #pragma unroll
        for (int mj = 0; mj < 4; mj++)
            #pragma unroll
            for (int r = 0; r < 4; r++) {
                float d2 = fmaxf(xnr[mi][r] + ynr[mj] - 2.f * acc[mi][mj][r], 0.f);
                rmin[mi][r] = fminf(rmin[mi][r], d2);
                cmin[mj]    = fminf(cmin[mj], d2);
            }

    #pragma unroll
    for (int m = 1; m < 16; m <<= 1)
        #pragma unroll
        for (int mi = 0; mi < 4; mi++)
            #pragma unroll
            for (int r = 0; r < 4; r++)
                rmin[mi][r] = fminf(rmin[mi][r], __shfl_xor(rmin[mi][r], m, 64));
    if (tx == 0) {
        #pragma unroll
        for (int mi = 0; mi < 4; mi++)
            #pragma unroll
            for (int r = 0; r < 4; r++)
                atomicMin(&rowmin[rbase + mi * 16 + quad * 4 + r], __float_as_uint(rmin[mi][r]));
    }
    #pragma unroll
    for (int m = 16; m < 64; m <<= 1)
        #pragma unroll
        for (int mj = 0; mj < 4; mj++)
            cmin[mj] = fminf(cmin[mj], __shfl_xor(cmin[mj], m, 64));
    if (quad == 0) {
        #pragma unroll
        for (int mj = 0; mj < 4; mj++)
            atomicMin(&colmin[cbase + mj * 16 + tx], __float_as_uint(cmin[mj]));
    }
}

// ============================ FALLBACK PATH (R2, proven) ============================
__global__ __launch_bounds__(256) void norms_kernel(const float* __restrict__ X,
                                                    const float* __restrict__ Y,
                                                    float* __restrict__ xn,
                                                    float* __restrict__ yn) {
    int w = threadIdx.x >> 6, lane = threadIdx.x & 63;
    long rid = (long)blockIdx.x * 4 + w;
    bool isY = rid >= (long)BC * N;
    long row = isY ? rid - (long)BC * N : rid;
    const float* src = (isY ? Y : X) + row * D;
    float s = 0.f;
    #pragma unroll
    for (int q = 0; q < 4; q++) {
        float4 v = ((const float4*)src)[lane + q * 64];
        s += v.x * v.x + v.y * v.y + v.z * v.z + v.w * v.w;
    }
    #pragma unroll
    for (int m = 1; m < 64; m <<= 1) s += __shfl_xor(s, m, 64);
    if (lane == 0) (isY ? yn : xn)[row] = s;
}

__global__ __launch_bounds__(256) void tile_conv_kernel(const float* __restrict__ X,
                                                        const float* __restrict__ Y,
                                                        const float* __restrict__ xn,
                                                        const float* __restrict__ yn,
                                                        unsigned* __restrict__ rowmin,
                                                        unsigned* __restrict__ colmin) {
    __shared__ unsigned short Xs[TILE * SKF];
    __shared__ unsigned short Ys[TILE * SKF];
    int bc = blockIdx.z, tn = blockIdx.y, tm = blockIdx.x;
    const float* Xb = X + ((size_t)bc * N + (size_t)tn * TILE) * D;
    const float* Yb = Y + ((size_t)bc * N + (size_t)tm * TILE) * D;

    int t = threadIdx.x;
    int srow = t >> 3, sq = t & 7;
    int wave = t >> 6, lane = t & 63;
    int wr = wave >> 1, wc = wave & 1;
    int quad = lane >> 4, tx = lane & 15;

    f32x4 acc[4][4];
    #pragma unroll
    for (int i = 0; i < 4; i++)
        #pragma unroll
        for (int j = 0; j < 4; j++) acc[i][j] = (f32x4)0.f;

    float4 xv[4], yv[4];
    #pragma unroll
    for (int i = 0; i < 4; i++) {
        xv[i] = *(const float4*)(Xb + (size_t)(srow + i * 32) * D + sq * 4);
        yv[i] = *(const float4*)(Yb + (size_t)(srow + i * 32) * D + sq * 4);
    }

    for (int k0 = 0; k0 < D; k0 += 32) {
        __syncthreads();
        #pragma unroll
        for (int i = 0; i < 4; i++) {
            uint2 px; px.x = pk_bf16(xv[i].x, xv[i].y); px.y = pk_bf16(xv[i].z, xv[i].w);
            *(uint2*)&Xs[(srow + i * 32) * SKF + sq * 4] = px;
            uint2 py; py.x = pk_bf16(yv[i].x, yv[i].y); py.y = pk_bf16(yv[i].z, yv[i].w);
            *(uint2*)&Ys[(srow + i * 32) * SKF + sq * 4] = py;
        }
        __syncthreads();
        if (k0 + 32 < D) {
            #pragma unroll
            for (int i = 0; i < 4; i++) {
                xv[i] = *(const float4*)(Xb + (size_t)(srow + i * 32) * D + k0 + 32 + sq * 4);
                yv[i] = *(const float4*)(Yb + (size_t)(srow + i * 32) * D + k0 + 32 + sq * 4);
            }
        }
        short8 af[4], bg[4];
        #pragma unroll
        for (int mi = 0; mi < 4; mi++)
            af[mi] = *(const short8*)&Xs[(wr * 64 + mi * 16 + tx) * SKF + quad * 8];
        #pragma unroll
        for (int mj = 0; mj < 4; mj++)
            bg[mj] = *(const short8*)&Ys[(wc * 64 + mj * 16 + tx) * SKF + quad * 8];
        #pragma unroll
        for (int mi = 0; mi < 4; mi++)
            #pragma unroll
            for (int mj = 0; mj < 4; mj++)
                acc[mi][mj] = __builtin_amdgcn_mfma_f32_16x16x32_bf16(af[mi], bg[mj], acc[mi][mj], 0, 0, 0);
    }

    int rbase = bc * N + tn * TILE + wr * 64;
    int cbase = bc * N + tm * TILE + wc * 64;
    float xnr[4][4], ynr[4];
    #pragma unroll
    for (int mi = 0; mi < 4; mi++)
        #pragma unroll
        for (int r = 0; r < 4; r++) xnr[mi][r] = xn[rbase + mi * 16 + quad * 4 + r];
    #pragma unroll
    for (int mj = 0; mj < 4; mj++) ynr[mj] = yn[cbase + mj * 16 + tx];

    float rmin[4][4], cmin[4];
    #pragma unroll
    for (int mi = 0; mi < 4; mi++)
        #pragma unroll
        for (int r = 0; r < 4; r++) rmin[mi][r] = FINF;
    #pragma unroll
    for (int mj = 0; mj < 4; mj++) cmin[mj] = FINF;

    #pragma unroll
    for (int mi = 0; mi < 4; mi++)
        #pragma unroll
        for (int mj = 0; mj < 4; mj++)
            #pragma unroll
            for (int r = 0; r < 4; r++) {
                float d2 = fmaxf(xnr[mi][r] + ynr[mj] - 2.f * acc[mi][mj][r], 0.f);
                rmin[mi][r] = fminf(rmin[mi][r], d2);
                cmin[mj]    = fminf(cmin[mj], d2);
            }

    #pragma unroll
    for (int m = 1; m < 16; m <<= 1)
        #pragma unroll
        for (int mi = 0; mi < 4; mi++)
            #pragma unroll
            for (int r = 0; r < 4; r++)
                rmin[mi][r] = fminf(rmin[mi][r], __shfl_xor(rmin[mi][r], m, 64));
    if (tx == 0) {
        #pragma unroll
        for (int mi = 0; mi < 4; mi++)
            #pragma unroll
            for (int r = 0; r < 4; r++)
                atomicMin(&rowmin[rbase + mi * 16 + quad * 4 + r], __float_as_uint(rmin[mi][r]));
    }
    #pragma unroll
    for (int m = 16; m < 64; m <<= 1)
        #pragma unroll
        for (int mj = 0; mj < 4; mj++)
            cmin[mj] = fminf(cmin[mj], __shfl_xor(cmin[mj], m, 64));
    if (quad == 0) {
        #pragma unroll
        for (int mj = 0; mj < 4; mj++)
            atomicMin(&colmin[cbase + mj * 16 + tx], __float_as_uint(cmin[mj]));
    }
}

// ---- Kernel 3: per-bc max over row/col mins, sqrt, mean over bc ----
__global__ __launch_bounds__(256) void finalize_kernel(const unsigned* __restrict__ rowmin,
                                                       const unsigned* __restrict__ colmin,
                                                       float* __restrict__ out) {
    int bc = blockIdx.x;
    float v = 0.f;
    for (int i = threadIdx.x; i < N; i += 256) {
        v = fmaxf(v, __uint_as_float(rowmin[bc * N + i]));
        v = fmaxf(v, __uint_as_float(colmin[bc * N + i]));
    }
    #pragma unroll
    for (int m = 1; m < 64; m <<= 1) v = fmaxf(v, __shfl_xor(v, m, 64));
    __shared__ float ws[4];
    int lane = threadIdx.x & 63, w = threadIdx.x >> 6;
    if (lane == 0) ws[w] = v;
    __syncthreads();
    if (threadIdx.x == 0) {
        float m = fmaxf(fmaxf(ws[0], ws[1]), fmaxf(ws[2], ws[3]));
        atomicAdd(out, sqrtf(m) * (1.0f / (float)BC));
    }
}

extern "C" void kernel_launch(void* const* d_in, const int* in_sizes, int n_in,
                              void* d_out, int out_size, void* d_ws, size_t ws_size,
                              hipStream_t stream) {
    const float* X = (const float*)d_in[0];   // input  [8,3,1024,1024]
    const float* Y = (const float*)d_in[1];   // target [8,3,1024,1024]
    float* out = (float*)d_out;               // scalar

    // ws layout: rowmin[24K u32] | colmin[24K u32] | xn[24K f32] | yn[24K f32] | Xf8 | Yf8
    unsigned* rowmin = (unsigned*)d_ws;
    unsigned* colmin = rowmin + BC * N;
    float* xn = (float*)(colmin + BC * N);
    float* yn = xn + BC * N;
    size_t head = (size_t)4 * BC * N * 4;            // 384 KB
    size_t f8_bytes = (size_t)BC * N * D;            // 25.17 MB each

    hipMemsetAsync(d_ws, 0xFF, (size_t)2 * BC * N * 4, stream);   // rowmin/colmin = +inf bits
    hipMemsetAsync(d_out, 0, sizeof(float), stream);
    // xn/yn need no memset: both prep paths fully overwrite every norm.

    // ws_size is constant across calls, so this branch is graph-capture safe.
    if (ws_size >= head + 2 * f8_bytes) {
        unsigned char* Xf8 = (unsigned char*)d_ws + head;
        unsigned char* Yf8 = Xf8 + f8_bytes;
        prep_kernel<<<1536, 256, 0, stream>>>(X, Y, Xf8, Yf8, xn, yn);
        tile_f8_kernel<<<1536, 256, 0, stream>>>(Xf8, Yf8, xn, yn, rowmin, colmin);
    } else {
        dim3 grid(N / TILE, N / TILE, BC);
        norms_kernel<<<2 * BC * N / 4, 256, 0, stream>>>(X, Y, xn, yn);
        tile_conv_kernel<<<grid, 256, 0, stream>>>(X, Y, xn, yn, rowmin, colmin);
    }
    finalize_kernel<<<BC, 256, 0, stream>>>(rowmin, colmin, out);
}

// Round 3
// 268.440 us; speedup vs baseline: 1.0701x; 1.0701x over previous
//
#include <hip/hip_runtime.h>
#include <math.h>

// Problem constants (fixed by reference: B=8, C=3, H=W=1024)
constexpr int BC = 24;     // B*C point-set pairs
constexpr int N  = 1024;   // points per set
constexpr int D  = 1024;   // point dimension
constexpr int TILE = 128;  // 128x128 output tile per block
constexpr int SKF = 40;    // fallback kernel LDS stride (bf16)

typedef short short8 __attribute__((ext_vector_type(8)));
typedef float f32x4  __attribute__((ext_vector_type(4)));
typedef long lng2    __attribute__((ext_vector_type(2)));   // two i64 fp8 fragments

#define FINF 3.402823466e+38f

// ---- Swizzled fp8 layout (used identically by prep-write and tile-read) ----
// Super-tile ST = (bc, R = row>>4, Kp = k>>6): 16 rows x 64 k = 1024 fp8 = 1 KB.
// Within: r16 = row&15, dose = (k>>5)&1, quad = (k>>3)&3, j = k&7.
// lane = r16 | (quad<<4); flat byte = ST*1024 + lane*16 + dose*8 + j.
// A wave's fragment pair (doses 0,1 of one 16-row tile) = one coalesced 1-KB
// global_load_dwordx4 (16 B/lane). Within-i64 k-order cancels between A and B.
//
// R2 lesson (measured): putting the permutation on the STORE side inflates
// WRITE_SIZE 52->86 MB (partial-line writebacks don't fully combine in L2)
// and costs +20 us. Permutation must ride the LOAD side: L3 absorbs gather
// re-reads (FETCH_SIZE ~98 MB either way), HBM writes must stay full-line.

// Pack two fp32 -> two bf16 (fallback path only). HW-verified R2-R5.
__device__ inline unsigned pk_bf16(float a, float b) {
    unsigned ua = __float_as_uint(a) + 0x8000u;
    unsigned ub = __float_as_uint(b) + 0x8000u;
    return __builtin_amdgcn_perm(ub, ua, 0x07060302);
}

// 4 floats -> one 32-bit word of 4 fp8-e4m3 (OCP on gfx950), RTNE.
__device__ inline int pk_fp8x4(float a, float b, float c, float d) {
    int w = __builtin_amdgcn_cvt_pk_fp8_f32(a, b, 0, false);   // bytes 0,1
    w = __builtin_amdgcn_cvt_pk_fp8_f32(c, d, w, true);        // bytes 2,3
    return w;
}

// ============================ FAST PATH ============================
// ---- Kernel 1f (R0 form, 85 us proven): persistent pipelined swizzle-convert
// (fp32 -> fp8, gather-read / contiguous-store) + norms ----
// 49152 super-tiles total (2 tensors x 24576); 3072 blocks x 4 waves x 4 STs.
__global__ __launch_bounds__(256) void prep_kernel(const float* __restrict__ X,
                                                   const float* __restrict__ Y,
                                                   unsigned char* __restrict__ Xf8,
                                                   unsigned char* __restrict__ Yf8,
                                                   float* __restrict__ xn,
                                                   float* __restrict__ yn) {
    int wave = threadIdx.x >> 6, lane = threadIdx.x & 63;
    int r16 = lane & 15, quad = lane >> 4;
    int wid = blockIdx.x * 4 + wave;              // 0 .. 12287

    // Stage register sets for 2-deep software pipeline.
    float4 c0, c1, c2, c3;                        // current ST's 16 floats
    float4 n0, n1, n2, n3;                        // next ST's 16 floats

    // st -> source pointer for this lane (k-span: Kp*64 + dose*32 + quad*8).
    auto src_of = [&](int st) -> const float* {
        bool isY = st >= 24576;
        int s = isY ? st - 24576 : st;
        int bc = s >> 10, rkp = s & 1023;
        int R = rkp >> 4, Kp = rkp & 15;
        return (isY ? Y : X) + ((size_t)bc * N + R * 16 + r16) * D + Kp * 64 + quad * 8;
    };

    {   // prologue: load ST for it=0
        const float* p = src_of(wid);
        c0 = *(const float4*)p;        c1 = *(const float4*)(p + 4);
        c2 = *(const float4*)(p + 32); c3 = *(const float4*)(p + 36);
    }
    #pragma unroll
    for (int it = 0; it < 4; it++) {
        int st = wid + it * 12288;
        if (it < 3) {   // issue next ST's loads before converting current
            const float* p = src_of(wid + (it + 1) * 12288);
            n0 = *(const float4*)p;        n1 = *(const float4*)(p + 4);
            n2 = *(const float4*)(p + 32); n3 = *(const float4*)(p + 36);
        }
        bool isY = st >= 24576;
        int s = isY ? st - 24576 : st;
        uint4 w;
        w.x = (unsigned)pk_fp8x4(c0.x, c0.y, c0.z, c0.w);   // dose0 j0..3
        w.y = (unsigned)pk_fp8x4(c1.x, c1.y, c1.z, c1.w);   // dose0 j4..7
        w.z = (unsigned)pk_fp8x4(c2.x, c2.y, c2.z, c2.w);   // dose1 j0..3
        w.w = (unsigned)pk_fp8x4(c3.x, c3.y, c3.z, c3.w);   // dose1 j4..7
        *(uint4*)((isY ? Yf8 : Xf8) + (size_t)s * 1024 + lane * 16) = w;

        // Row-norm partial (exact fp32) for this 64-k span; reduce over quads.
        float sm = c0.x*c0.x + c0.y*c0.y + c0.z*c0.z + c0.w*c0.w
                 + c1.x*c1.x + c1.y*c1.y + c1.z*c1.z + c1.w*c1.w
                 + c2.x*c2.x + c2.y*c2.y + c2.z*c2.z + c2.w*c2.w
                 + c3.x*c3.x + c3.y*c3.y + c3.z*c3.z + c3.w*c3.w;
        sm += __shfl_xor(sm, 16, 64);
        sm += __shfl_xor(sm, 32, 64);
        if (quad == 0) {
            int bc = s >> 10, R = (s & 1023) >> 4;
            atomicAdd(&(isY ? yn : xn)[bc * N + R * 16 + r16], sm);
        }
        c0 = n0; c1 = n1; c2 = n2; c3 = n3;
    }
}

// ---- Kernel 2g: zero-LDS fp8 MFMA tile kernel + XCD-chunked block swizzle ----
// R2 theory: raw blockIdx round-robins XCDs, so same-bc tiles (which share the
// whole 2 MB fp8 working set) scatter across all 8 XCDs -> per-XCD working set
// ~12 bc = 24 MB >> 4 MB L2 -> every frag load is an L3 round-trip (~4x slower
// than L2). Chunked remap (bijective, 1536 = 8*192): each XCD gets 192
// logically-consecutive tiles = exactly 3 bc -> concurrent set ~4 MB, L2-hit.
__global__ __launch_bounds__(256, 3) void tile_f8_kernel(const unsigned char* __restrict__ Xf8,
                                                         const unsigned char* __restrict__ Yf8,
                                                         const float* __restrict__ xn,
                                                         const float* __restrict__ yn,
                                                         unsigned* __restrict__ rowmin,
                                                         unsigned* __restrict__ colmin) {
    int raw = blockIdx.x;             // HW round-robins raw id across 8 XCDs
    int id = (raw & 7) * 192 + (raw >> 3);   // XCD-chunked logical tile id
    int bc = id >> 6;
    int tn = (id >> 3) & 7, tm = id & 7;

    int wave = threadIdx.x >> 6, lane = threadIdx.x & 63;
    int wr = wave >> 1, wc = wave & 1;      // wave tile: rows wr*64, cols wc*64
    int quad = lane >> 4, tx = lane & 15;

    const unsigned char* Xb = Xf8 + (size_t)bc * 1024 * 1024;   // 1024 STs x 1 KB per bc
    const unsigned char* Yb = Yf8 + (size_t)bc * 1024 * 1024;
    // A STs: R = tn*8 + wr*4 + mi (mi stride = 16 STs = 16 KB); Kp stride = 1 KB.
    const unsigned char* ax = Xb + (size_t)(tn * 8 + wr * 4) * 16 * 1024 + lane * 16;
    const unsigned char* by = Yb + (size_t)(tm * 8 + wc * 4) * 16 * 1024 + lane * 16;

    f32x4 acc[4][4];
    #pragma unroll
    for (int i = 0; i < 4; i++)
        #pragma unroll
        for (int j = 0; j < 4; j++) acc[i][j] = (f32x4)0.f;

    // 2-deep register pipeline over 16 Kp super-doses (2 MFMA doses each).
    lng2 a[2][4], b[2][4];
    #pragma unroll
    for (int mi = 0; mi < 4; mi++) {
        a[0][mi] = *(const lng2*)(ax + mi * 16384);
        b[0][mi] = *(const lng2*)(by + mi * 16384);
    }
    #pragma unroll
    for (int Kp = 0; Kp < 16; Kp++) {
        int cur = Kp & 1, nxt = cur ^ 1;
        if (Kp < 15) {
            #pragma unroll
            for (int mi = 0; mi < 4; mi++) {
                a[nxt][mi] = *(const lng2*)(ax + mi * 16384 + (Kp + 1) * 1024);
                b[nxt][mi] = *(const lng2*)(by + mi * 16384 + (Kp + 1) * 1024);
            }
        }
        #pragma unroll
        for (int mi = 0; mi < 4; mi++)
            #pragma unroll
            for (int mj = 0; mj < 4; mj++)
                acc[mi][mj] = __builtin_amdgcn_mfma_f32_16x16x32_fp8_fp8(a[cur][mi].x, b[cur][mj].x, acc[mi][mj], 0, 0, 0);
        #pragma unroll
        for (int mi = 0; mi < 4; mi++)
            #pragma unroll
            for (int mj = 0; mj < 4; mj++)
                acc[mi][mj] = __builtin_amdgcn_mfma_f32_16x16x32_fp8_fp8(a[cur][mi].y, b[cur][mj].y, acc[mi][mj], 0, 0, 0);
    }

    // Epilogue. D-layout (shape-determined, dtype-independent): row = quad*4 + r, col = tx.
    int rbase = bc * N + tn * TILE + wr * 64;
    int cbase = bc * N + tm * TILE + wc * 64;
    float xnr[4][4], ynr[4];
    #pragma unroll
    for (int mi = 0; mi < 4; mi++)
        #pragma unroll
        for (int r = 0; r < 4; r++) xnr[mi][r] = xn[rbase + mi * 16 + quad * 4 + r];
    #pragma unroll
    for (int mj = 0; mj < 4; mj++) ynr[mj] = yn[cbase + mj * 16 + tx];

    float rmin[4][4], cmin[4];
    #pragma unroll
    for (int mi = 0; mi < 4; mi++)
        #pragma unroll
        for (int r = 0; r < 4; r++) rmin[mi][r] = FINF;
    #pragma unroll
    for (int mj = 0; mj < 4; mj++) cmin[mj] = FINF;

    #pragma unroll
    for (int mi = 0; mi < 4; mi++)
        #pragma unroll
        for (int mj = 0; mj < 4; mj++)
            #pragma unroll
            for (int r = 0; r < 4; r++) {
                float d2 = fmaxf(xnr[mi][r] + ynr[mj] - 2.f * acc[mi][mj][r], 0.f);
                rmin[mi][r] = fminf(rmin[mi][r], d2);
                cmin[mj]    = fminf(cmin[mj], d2);
            }

    #pragma unroll
    for (int m = 1; m < 16; m <<= 1)
        #pragma unroll
        for (int mi = 0; mi < 4; mi++)
            #pragma unroll
            for (int r = 0; r < 4; r++)
                rmin[mi][r] = fminf(rmin[mi][r], __shfl_xor(rmin[mi][r], m, 64));
    if (tx == 0) {
        #pragma unroll
        for (int mi = 0; mi < 4; mi++)
            #pragma unroll
            for (int r = 0; r < 4; r++)
                atomicMin(&rowmin[rbase + mi * 16 + quad * 4 + r], __float_as_uint(rmin[mi][r]));
    }
    #pragma unroll
    for (int m = 16; m < 64; m <<= 1)
        #pragma unroll
        for (int mj = 0; mj < 4; mj++)
            cmin[mj] = fminf(cmin[mj], __shfl_xor(cmin[mj], m, 64));
    if (quad == 0) {
        #pragma unroll
        for (int mj = 0; mj < 4; mj++)
            atomicMin(&colmin[cbase + mj * 16 + tx], __float_as_uint(cmin[mj]));
    }
}

// ============================ FALLBACK PATH (R2, proven) ============================
__global__ __launch_bounds__(256) void norms_kernel(const float* __restrict__ X,
                                                    const float* __restrict__ Y,
                                                    float* __restrict__ xn,
                                                    float* __restrict__ yn) {
    int w = threadIdx.x >> 6, lane = threadIdx.x & 63;
    long rid = (long)blockIdx.x * 4 + w;
    bool isY = rid >= (long)BC * N;
    long row = isY ? rid - (long)BC * N : rid;
    const float* src = (isY ? Y : X) + row * D;
    float s = 0.f;
    #pragma unroll
    for (int q = 0; q < 4; q++) {
        float4 v = ((const float4*)src)[lane + q * 64];
        s += v.x * v.x + v.y * v.y + v.z * v.z + v.w * v.w;
    }
    #pragma unroll
    for (int m = 1; m < 64; m <<= 1) s += __shfl_xor(s, m, 64);
    if (lane == 0) (isY ? yn : xn)[row] = s;
}

__global__ __launch_bounds__(256) void tile_conv_kernel(const float* __restrict__ X,
                                                        const float* __restrict__ Y,
                                                        const float* __restrict__ xn,
                                                        const float* __restrict__ yn,
                                                        unsigned* __restrict__ rowmin,
                                                        unsigned* __restrict__ colmin) {
    __shared__ unsigned short Xs[TILE * SKF];
    __shared__ unsigned short Ys[TILE * SKF];
    int bc = blockIdx.z, tn = blockIdx.y, tm = blockIdx.x;
    const float* Xb = X + ((size_t)bc * N + (size_t)tn * TILE) * D;
    const float* Yb = Y + ((size_t)bc * N + (size_t)tm * TILE) * D;

    int t = threadIdx.x;
    int srow = t >> 3, sq = t & 7;
    int wave = t >> 6, lane = t & 63;
    int wr = wave >> 1, wc = wave & 1;
    int quad = lane >> 4, tx = lane & 15;

    f32x4 acc[4][4];
    #pragma unroll
    for (int i = 0; i < 4; i++)
        #pragma unroll
        for (int j = 0; j < 4; j++) acc[i][j] = (f32x4)0.f;

    float4 xv[4], yv[4];
    #pragma unroll
    for (int i = 0; i < 4; i++) {
        xv[i] = *(const float4*)(Xb + (size_t)(srow + i * 32) * D + sq * 4);
        yv[i] = *(const float4*)(Yb + (size_t)(srow + i * 32) * D + sq * 4);
    }

    for (int k0 = 0; k0 < D; k0 += 32) {
        __syncthreads();
        #pragma unroll
        for (int i = 0; i < 4; i++) {
            uint2 px; px.x = pk_bf16(xv[i].x, xv[i].y); px.y = pk_bf16(xv[i].z, xv[i].w);
            *(uint2*)&Xs[(srow + i * 32) * SKF + sq * 4] = px;
            uint2 py; py.x = pk_bf16(yv[i].x, yv[i].y); py.y = pk_bf16(yv[i].z, yv[i].w);
            *(uint2*)&Ys[(srow + i * 32) * SKF + sq * 4] = py;
        }
        __syncthreads();
        if (k0 + 32 < D) {
            #pragma unroll
            for (int i = 0; i < 4; i++) {
                xv[i] = *(const float4*)(Xb + (size_t)(srow + i * 32) * D + k0 + 32 + sq * 4);
                yv[i] = *(const float4*)(Yb + (size_t)(srow + i * 32) * D + k0 + 32 + sq * 4);
            }
        }
        short8 af[4], bg[4];
        #pragma unroll
        for (int mi = 0; mi < 4; mi++)
            af[mi] = *(const short8*)&Xs[(wr * 64 + mi * 16 + tx) * SKF + quad * 8];
        #pragma unroll
        for (int mj = 0; mj < 4; mj++)
            bg[mj] = *(const short8*)&Ys[(wc * 64 + mj * 16 + tx) * SKF + quad * 8];
        #pragma unroll
        for (int mi = 0; mi < 4; mi++)
            #pragma unroll
            for (int mj = 0; mj < 4; mj++)
                acc[mi][mj] = __builtin_amdgcn_mfma_f32_16x16x32_bf16(af[mi], bg[mj], acc[mi][mj], 0, 0, 0);
    }

    int rbase = bc * N + tn * TILE + wr * 64;
    int cbase = bc * N + tm * TILE + wc * 64;
    float xnr[4][4], ynr[4];
    #pragma unroll
    for (int mi = 0; mi < 4; mi++)
        #pragma unroll
        for (int r = 0; r < 4; r++) xnr[mi][r] = xn[rbase + mi * 16 + quad * 4 + r];
    #pragma unroll
    for (int mj = 0; mj < 4; mj++) ynr[mj] = yn[cbase + mj * 16 + tx];

    float rmin[4][4], cmin[4];
    #pragma unroll
    for (int mi = 0; mi < 4; mi++)
        #pragma unroll
        for (int r = 0; r < 4; r++) rmin[mi][r] = FINF;
    #pragma unroll
    for (int mj = 0; mj < 4; mj++) cmin[mj] = FINF;

    #pragma unroll
    for (int mi = 0; mi < 4; mi++)
        #pragma unroll
        for (int mj = 0; mj < 4; mj++)
            #pragma unroll
            for (int r = 0; r < 4; r++) {
                float d2 = fmaxf(xnr[mi][r] + ynr[mj] - 2.f * acc[mi][mj][r], 0.f);
                rmin[mi][r] = fminf(rmin[mi][r], d2);
                cmin[mj]    = fminf(cmin[mj], d2);
            }

    #pragma unroll
    for (int m = 1; m < 16; m <<= 1)
        #pragma unroll
        for (int mi = 0; mi < 4; mi++)
            #pragma unroll
            for (int r = 0; r < 4; r++)
                rmin[mi][r] = fminf(rmin[mi][r], __shfl_xor(rmin[mi][r], m, 64));
    if (tx == 0) {
        #pragma unroll
        for (int mi = 0; mi < 4; mi++)
            #pragma unroll
            for (int r = 0; r < 4; r++)
                atomicMin(&rowmin[rbase + mi * 16 + quad * 4 + r], __float_as_uint(rmin[mi][r]));
    }
    #pragma unroll
    for (int m = 16; m < 64; m <<= 1)
        #pragma unroll
        for (int mj = 0; mj < 4; mj++)
            cmin[mj] = fminf(cmin[mj], __shfl_xor(cmin[mj], m, 64));
    if (quad == 0) {
        #pragma unroll
        for (int mj = 0; mj < 4; mj++)
            atomicMin(&colmin[cbase + mj * 16 + tx], __float_as_uint(cmin[mj]));
    }
}

// ---- Kernel 3: per-bc max over row/col mins, sqrt, mean over bc ----
__global__ __launch_bounds__(256) void finalize_kernel(const unsigned* __restrict__ rowmin,
                                                       const unsigned* __restrict__ colmin,
                                                       float* __restrict__ out) {
    int bc = blockIdx.x;
    float v = 0.f;
    for (int i = threadIdx.x; i < N; i += 256) {
        v = fmaxf(v, __uint_as_float(rowmin[bc * N + i]));
        v = fmaxf(v, __uint_as_float(colmin[bc * N + i]));
    }
    #pragma unroll
    for (int m = 1; m < 64; m <<= 1) v = fmaxf(v, __shfl_xor(v, m, 64));
    __shared__ float ws[4];
    int lane = threadIdx.x & 63, w = threadIdx.x >> 6;
    if (lane == 0) ws[w] = v;
    __syncthreads();
    if (threadIdx.x == 0) {
        float m = fmaxf(fmaxf(ws[0], ws[1]), fmaxf(ws[2], ws[3]));
        atomicAdd(out, sqrtf(m) * (1.0f / (float)BC));
    }
}

extern "C" void kernel_launch(void* const* d_in, const int* in_sizes, int n_in,
                              void* d_out, int out_size, void* d_ws, size_t ws_size,
                              hipStream_t stream) {
    const float* X = (const float*)d_in[0];   // input  [8,3,1024,1024]
    const float* Y = (const float*)d_in[1];   // target [8,3,1024,1024]
    float* out = (float*)d_out;               // scalar

    // ws layout: rowmin[24K u32] | colmin[24K u32] | xn[24K f32] | yn[24K f32] | Xf8 | Yf8
    unsigned* rowmin = (unsigned*)d_ws;
    unsigned* colmin = rowmin + BC * N;
    float* xn = (float*)(colmin + BC * N);
    float* yn = xn + BC * N;
    size_t head = (size_t)4 * BC * N * 4;            // 384 KB
    size_t f8_bytes = (size_t)BC * N * D;            // 25.17 MB each

    hipMemsetAsync(d_ws, 0xFF, (size_t)2 * BC * N * 4, stream);   // rowmin/colmin = +inf bits
    hipMemsetAsync(xn, 0, (size_t)2 * BC * N * 4, stream);        // xn/yn = 0 (atomic targets)
    hipMemsetAsync(d_out, 0, sizeof(float), stream);

    // ws_size is constant across calls, so this branch is graph-capture safe.
    if (ws_size >= head + 2 * f8_bytes) {
        unsigned char* Xf8 = (unsigned char*)d_ws + head;
        unsigned char* Yf8 = Xf8 + f8_bytes;
        prep_kernel<<<3072, 256, 0, stream>>>(X, Y, Xf8, Yf8, xn, yn);
        tile_f8_kernel<<<1536, 256, 0, stream>>>(Xf8, Yf8, xn, yn, rowmin, colmin);
    } else {
        dim3 grid(N / TILE, N / TILE, BC);
        norms_kernel<<<2 * BC * N / 4, 256, 0, stream>>>(X, Y, xn, yn);
        tile_conv_kernel<<<grid, 256, 0, stream>>>(X, Y, xn, yn, rowmin, colmin);
    }
    finalize_kernel<<<BC, 256, 0, stream>>>(rowmin, colmin, out);
}